// Round 8
// baseline (308.827 us; speedup 1.0000x reference)
//
#include <hip/hip_runtime.h>
#include <math.h>

#define B     32
#define CIN   128
#define NN    8192
#define N1    8190     // output length after k=3 valid conv
#define CH    10
#define TPB   64       // ONE wave per block: no inter-wave hazards -> the
                       // counted-vmcnt pipeline needs NO barriers at all
#define TOUT  60       // diag outputs per block
#define NTILE 137      // ceil(8190/60)
#define COLS  68       // staged cols per channel: [t0-4, t0+63], 17 float4
#define F4PC  17       // float4 per channel row
#define CPC   8        // channels per chunk
#define NCHK  16       // chunks
#define NBUF  4        // pipeline depth: 4 chunks (12 loads, 8.7KB) in flight

// K0: transpose w1[o][ci][k] -> wT[ci][o*3+k] (rows padded to 32 floats)
// so k_main's per-channel 30 weights are contiguous wave-uniform s_loads.
__global__ void k0_prep(const float* __restrict__ w1, float* __restrict__ wT)
{
    const int i = blockIdx.x * 256 + threadIdx.x;     // 0..4095
    if (i < CIN * 32) {
        const int ci = i >> 5, r = i & 31;
        float v = 0.f;
        if (r < 30) {
            const int o = r / 3, k = r - o * 3;
            v = w1[(o * CIN + ci) * 3 + k];
        }
        wT[i] = v;
    }
}

typedef __attribute__((address_space(1))) void g_void;
typedef __attribute__((address_space(3))) void l_void;

__device__ __forceinline__ void gld16(const float* g, float* l)
{
    // async global->LDS, 16B per lane; LDS dest = wave-uniform base + lane*16
    __builtin_amdgcn_global_load_lds((g_void*)g, (l_void*)l, 16, 0, 0);
}

// Counted waits (T4): vmcnt retires IN ISSUE ORDER; in-loop issue order is
// serialized by the asm "memory" ops (R6 validated this with exact absmax).
// Prologue order is NOT trusted -> one full drain after prologue (R5 lesson).
#define WAITVM(N)  asm volatile("s_waitcnt vmcnt(" #N ")" ::: "memory")
#define WAITLGKM() asm volatile("s_waitcnt lgkmcnt(0)" ::: "memory")

// Stage one f4: f4 index i -> buf bytes [16i,16i+16).
// Per-lane i = uniform base + lane, so dest = uniform + lane*16 (HW pattern).
__device__ __forceinline__ void stage_one(const float* __restrict__ rowbase,
                                          float* buf, int i, int scol0)
{
    const int row = (int)((unsigned)i / (unsigned)F4PC);
    int col = scol0 + (i - row * F4PC) * 4;
    col = col < 0 ? 0 : (col > NN - 4 ? NN - 4 : col);  // clamped slots are
    gld16(rowbase + (size_t)row * NN + col, buf + (size_t)i * 4); // gvalid-masked
}

// Stage chunk c: 8 ch x 17 f4 = 136 f4, one wave: 64 + 64 + 8-lane tail.
// 3 vmcnt events per call (masked tail still issues: lanes 0-7 always live;
// R6's exact-absmax run empirically validated this count).
__device__ __forceinline__ void stage_chunk(const float* __restrict__ sigb, int c,
                                            float* buf, int tid, int scol0)
{
    const float* rowbase = sigb + (size_t)(c * CPC) * NN;
    stage_one(rowbase, buf, tid, scol0);
    stage_one(rowbase, buf, 64 + tid, scol0);
    if (tid < 8)
        stage_one(rowbase, buf, 128 + tid, scol0);
}

// FMA over one staged chunk. LDS float idx tid+2 <=> col g = t0-2+tid.
__device__ __forceinline__ void chunkfma(const float* __restrict__ cur, int c,
                                         int tid, float (&y)[CH],
                                         const float* __restrict__ wT)
{
    const float* bl = cur + tid + 2;
#pragma unroll
    for (int j = 0; j < CPC; ++j) {
        const float s0 = bl[j * COLS + 0];
        const float s1 = bl[j * COLS + 1];
        const float s2 = bl[j * COLS + 2];
        const float* wrow = wT + (c * CPC + j) * 32;  // uniform -> s_loads
#pragma unroll
        for (int o = 0; o < CH; ++o) {
            y[o] = fmaf(wrow[o * 3 + 0], s0, y[o]);
            y[o] = fmaf(wrow[o * 3 + 1], s1, y[o]);
            y[o] = fmaf(wrow[o * 3 + 2], s2, y[o]);
        }
    }
}

// K_MAIN: whole pipeline per 60-output tile, ONE WAVE per block.
// R3(4-wave)/R7(1-wave) both landed 77-78us with prefetch-depth 1 + per-chunk
// vmcnt(0) drain: ~9.9k cyc/chunk vs 600cy compute -> queueing-latency-bound
// (only ~2KB in flight per wave; chip BW 1.0-1.4 TB/s, outstanding-limited).
// Fix: depth-4 counted-vmcnt pipeline with ZERO barriers (1 wave = no
// inter-wave hazards). Steady state keeps 12 loads (4 chunks, 8.7KB) in
// flight per wave: [WAITVM(9); fma c; lgkm(0); stage c+4], epilogue 9/6/3/0.
__global__ __launch_bounds__(TPB) void k_main(
    const float* __restrict__ sig, const float* __restrict__ wT,
    const float* __restrict__ b1, const float* __restrict__ w2, const float* __restrict__ b2,
    const float* __restrict__ wt, const float* __restrict__ bt,
    const float* __restrict__ w3, const float* __restrict__ b3,
    const float* __restrict__ cd, const float* __restrict__ cstp,
    float* __restrict__ outv, float* __restrict__ bsums)
{
    __shared__ float bufs[NBUF][CPC * COLS];  // 4 x 2176 B
    __shared__ float h2s[CH * TPB];           // 2560 B  [o][col]
    __shared__ float lsh[TPB], rsh[TPB];

    const int tid = threadIdx.x;
    const int b   = blockIdx.y;
    const int t0  = blockIdx.x * TOUT;
    const int scol0 = t0 - 4;                         // 4-col aligned (60bx%4==0)
    const int g   = t0 - 2 + tid;                     // h2 column of this thread
    const bool gvalid = (g >= 0) && (g < N1);
    const float* __restrict__ sigb = sig + (size_t)b * CIN * NN;

    float y[CH];
#pragma unroll
    for (int o = 0; o < CH; ++o) y[o] = b1[o];

    // ---- Phase 1 prologue: stage chunks 0-3, ONE full drain ----
    stage_chunk(sigb, 0, bufs[0], tid, scol0);
    __builtin_amdgcn_sched_barrier(0);
    stage_chunk(sigb, 1, bufs[1], tid, scol0);
    __builtin_amdgcn_sched_barrier(0);
    stage_chunk(sigb, 2, bufs[2], tid, scol0);
    __builtin_amdgcn_sched_barrier(0);
    stage_chunk(sigb, 3, bufs[3], tid, scol0);
    __syncthreads();                                  // vmcnt(0): chunks 0-3 in LDS

    // ---- steady loop: no barriers, counted vmcnt only ----
    for (int c = 0; c < 12; ++c) {
        WAITVM(9);                        // no-op c<4; steady: retire chunk c
        chunkfma(bufs[c & 3], c, tid, y, wT);
        WAITLGKM();                       // my LDS reads retired before DMA refill
        stage_chunk(sigb, c + 4, bufs[c & 3], tid, scol0);
    }
    // epilogue: outstanding 12 -> waits 9,6,3,0
    WAITVM(9); chunkfma(bufs[0], 12, tid, y, wT);
    WAITVM(6); chunkfma(bufs[1], 13, tid, y, wT);
    WAITVM(3); chunkfma(bufs[2], 14, tid, y, wT);
    WAITVM(0); chunkfma(bufs[3], 15, tid, y, wT);

    // conv2 (1x1) + relu -> LDS (zero outside [0,N1) for convT zero-padding)
#pragma unroll
    for (int o = 0; o < CH; ++o) y[o] = fmaxf(y[o], 0.f);
#pragma unroll
    for (int o = 0; o < CH; ++o) {
        float a = b2[o];
#pragma unroll
        for (int i = 0; i < CH; ++i) a = fmaf(w2[o * CH + i], y[i], a);
        h2s[o * TPB + tid] = gvalid ? fmaxf(a, 0.f) : 0.f;
    }
    __syncthreads();

    // convT + relu + 1x1 + sigmoid -> lr at s = t0 + tid (tid < 62)
    const int s = t0 + tid;
    if (tid < TOUT + 2 && s < NN) {
        float acc[CH];
#pragma unroll
        for (int o = 0; o < CH; ++o) acc[o] = bt[o];
#pragma unroll
        for (int i = 0; i < CH; ++i) {
            const float a0 = h2s[i * TPB + tid];      // h2[s-2]
            const float a1 = h2s[i * TPB + tid + 1];  // h2[s-1]
            const float a2 = h2s[i * TPB + tid + 2];  // h2[s]
            const float* wp = wt + i * CH * 3;        // contiguous uniform
#pragma unroll
            for (int o = 0; o < CH; ++o) {
                acc[o] = fmaf(wp[o * 3 + 0], a2, acc[o]);
                acc[o] = fmaf(wp[o * 3 + 1], a1, acc[o]);
                acc[o] = fmaf(wp[o * 3 + 2], a0, acc[o]);
            }
        }
        float l = b3[0], r = b3[1];
#pragma unroll
        for (int o = 0; o < CH; ++o) {
            const float h3 = fmaxf(acc[o], 0.f);
            l = fmaf(w3[o],      h3, l);
            r = fmaf(w3[CH + o], h3, r);
        }
        lsh[tid] = 1.f / (1.f + __expf(-l));
        rsh[tid] = 1.f / (1.f + __expf(-r));
    }
    __syncthreads();

    // tridiagonal update + log for t = t0 + tid (tid < TOUT)
    float vlog = 0.f;
    const int t = t0 + tid;
    if (tid < TOUT && t < N1) {
        const float c0 = cd[(size_t)b * (NN - 1) + t];
        const float c1 = cd[(size_t)b * (NN - 1) + t + 1];
        const float mi = c1 * rsh[tid + 1] + c0 * lsh[tid + 1];
        const float mo = rsh[tid] + lsh[tid + 2];
        vlog = __logf(cstp[0] * mi / mo);
        outv[(size_t)b * N1 + t] = vlog;
    }

    // block sum: single-wave shuffle reduce
    float vs = vlog;
#pragma unroll
    for (int off = 32; off > 0; off >>= 1) vs += __shfl_down(vs, off);
    if (tid == 0)
        bsums[blockIdx.y * NTILE + blockIdx.x] = vs;
}

// K3: every block redundantly reduces the 4384 bsums (L2-hot), subtracts mean.
__global__ __launch_bounds__(256) void k3_meansub(
    const float* __restrict__ bsums, float* __restrict__ outv, int n)
{
    __shared__ float red[256];
    const int tid = threadIdx.x;
    float s = 0.f;
    for (int i = tid; i < NTILE * B; i += 256) s += bsums[i];
    red[tid] = s;
    __syncthreads();
#pragma unroll
    for (int st = 128; st > 0; st >>= 1) {
        if (tid < st) red[tid] += red[tid + st];
        __syncthreads();
    }
    const float mean = red[0] / (float)(B * N1);
    __syncthreads();
    const int i = blockIdx.x * 256 + tid;
    if (i < n) outv[i] -= mean;
}

extern "C" void kernel_launch(void* const* d_in, const int* in_sizes, int n_in,
                              void* d_out, int out_size, void* d_ws, size_t ws_size,
                              hipStream_t stream)
{
    const float* sig = (const float*)d_in[0];
    const float* cd  = (const float*)d_in[1];
    // d_in[2] = index_diag (1 for these shapes)
    const float* w1  = (const float*)d_in[3];
    const float* b1  = (const float*)d_in[4];
    const float* w2  = (const float*)d_in[5];
    const float* b2  = (const float*)d_in[6];
    const float* wt  = (const float*)d_in[7];
    const float* bt  = (const float*)d_in[8];
    const float* w3  = (const float*)d_in[9];
    const float* b3  = (const float*)d_in[10];
    const float* cst = (const float*)d_in[11];

    float* outv = (float*)d_out;

    // workspace layout (floats)
    float* ws   = (float*)d_ws;
    float* wT   = ws;                  // CIN*32 = 4096
    float* bsum = wT + CIN * 32;       // NTILE*B = 4384

    k0_prep   <<<dim3(16), dim3(256), 0, stream>>>(w1, wT);
    k_main    <<<dim3(NTILE, B), dim3(TPB), 0, stream>>>(sig, wT, b1, w2, b2,
                                                         wt, bt, w3, b3, cd, cst, outv, bsum);
    k3_meansub<<<dim3((out_size + 255) / 256), dim3(256), 0, stream>>>(bsum, outv, out_size);
}

// Round 9
// 273.370 us; speedup vs baseline: 1.1297x; 1.1297x over previous
//
#include <hip/hip_runtime.h>
#include <math.h>

#define B     32
#define CIN   128
#define NN    8192
#define N1    8190     // output length after k=3 valid conv
#define CH    10
#define TPB   64       // ONE wave per block (R7 structure, best-known 77.9us)
#define TOUT  60       // diag outputs per block
#define NTILE 137      // ceil(8190/60)
#define COLS  68       // staged cols per channel: [t0-4, t0+63], 17 float4
#define F4PC  17       // float4 per channel row
#define CPC   16       // channels per chunk (R7 had 8): halves the drain count
#define NCHK  8        // chunks (R7 had 16)

// K0: transpose w1[o][ci][k] -> wT[ci][o*3+k] (rows padded to 32 floats)
// so k_main's per-channel 30 weights are contiguous wave-uniform s_loads.
__global__ void k0_prep(const float* __restrict__ w1, float* __restrict__ wT)
{
    const int i = blockIdx.x * 256 + threadIdx.x;     // 0..4095
    if (i < CIN * 32) {
        const int ci = i >> 5, r = i & 31;
        float v = 0.f;
        if (r < 30) {
            const int o = r / 3, k = r - o * 3;
            v = w1[(o * CIN + ci) * 3 + k];
        }
        wT[i] = v;
    }
}

typedef __attribute__((address_space(1))) void g_void;
typedef __attribute__((address_space(3))) void l_void;

__device__ __forceinline__ void gld16(const float* g, float* l)
{
    // async global->LDS, 16B per lane; LDS dest = wave-uniform base + lane*16
    __builtin_amdgcn_global_load_lds((g_void*)g, (l_void*)l, 16, 0, 0);
}

// Stage one f4: f4 index i -> buf bytes [16i,16i+16).
__device__ __forceinline__ void stage_one(const float* __restrict__ rowbase,
                                          float* buf, int i, int scol0)
{
    const int row = (int)((unsigned)i / (unsigned)F4PC);
    int col = scol0 + (i - row * F4PC) * 4;
    col = col < 0 ? 0 : (col > NN - 4 ? NN - 4 : col);  // clamped slots are
    gld16(rowbase + (size_t)row * NN + col, buf + (size_t)i * 4); // gvalid-masked
}

// Stage chunk c: 16 ch x 17 f4 = 272 f4, one wave: 4 full passes + 16-lane tail.
__device__ __forceinline__ void stage_chunk(const float* __restrict__ sigb, int c,
                                            float* buf, int tid, int scol0)
{
    const float* rowbase = sigb + (size_t)(c * CPC) * NN;
    stage_one(rowbase, buf, tid, scol0);
    stage_one(rowbase, buf, 64 + tid, scol0);
    stage_one(rowbase, buf, 128 + tid, scol0);
    stage_one(rowbase, buf, 192 + tid, scol0);
    if (tid < 16)
        stage_one(rowbase, buf, 256 + tid, scol0);
}

// FMA over one staged chunk (16 channels). LDS float idx tid+2 <=> col g.
__device__ __forceinline__ void chunkfma(const float* __restrict__ cur, int c,
                                         int tid, float (&y)[CH],
                                         const float* __restrict__ wT)
{
    const float* bl = cur + tid + 2;
#pragma unroll
    for (int j = 0; j < CPC; ++j) {
        const float s0 = bl[j * COLS + 0];
        const float s1 = bl[j * COLS + 1];
        const float s2 = bl[j * COLS + 2];
        const float* wrow = wT + (c * CPC + j) * 32;  // uniform -> s_loads
#pragma unroll
        for (int o = 0; o < CH; ++o) {
            y[o] = fmaf(wrow[o * 3 + 0], s0, y[o]);
            y[o] = fmaf(wrow[o * 3 + 1], s1, y[o]);
            y[o] = fmaf(wrow[o * 3 + 2], s2, y[o]);
        }
    }
}

// K_MAIN: whole pipeline per 60-output tile, ONE WAVE per block.
// Evidence through R8: R3(4-wave)/R7(1-wave) both 77-78us with ~9.9k cy per
// chunk-drain vs 600cy compute; time invariant to memory source (R6's L3-hot
// dispatch = HBM dispatch) -> the cost per drain cycle looks FIXED, not
// per-byte. All fence/counted-vmcnt pipelines (R1/R6/R8) poisoned codegen
// and regressed 1.5-2x. So: amortize the drain instead. CPC 8->16 halves
// the number of drains at identical protocol (pure __syncthreads, no asm).
__global__ __launch_bounds__(TPB) void k_main(
    const float* __restrict__ sig, const float* __restrict__ wT,
    const float* __restrict__ b1, const float* __restrict__ w2, const float* __restrict__ b2,
    const float* __restrict__ wt, const float* __restrict__ bt,
    const float* __restrict__ w3, const float* __restrict__ b3,
    const float* __restrict__ cd, const float* __restrict__ cstp,
    float* __restrict__ outv, float* __restrict__ bsums)
{
    __shared__ float bufA[CPC * COLS];   // 4352 B
    __shared__ float bufB[CPC * COLS];   // 4352 B
    __shared__ float h2s[CH * TPB];      // 2560 B  [o][col]
    __shared__ float lsh[TPB], rsh[TPB];

    const int tid = threadIdx.x;
    const int b   = blockIdx.y;
    const int t0  = blockIdx.x * TOUT;
    const int scol0 = t0 - 4;                         // 4-col aligned (60bx%4==0)
    const int g   = t0 - 2 + tid;                     // h2 column of this thread
    const bool gvalid = (g >= 0) && (g < N1);
    const float* __restrict__ sigb = sig + (size_t)b * CIN * NN;

    float y[CH];
#pragma unroll
    for (int o = 0; o < CH; ++o) y[o] = b1[o];

    // ---- Phase 1: 8 chunks x 16 channels, double-buffered LDS staging ----
    stage_chunk(sigb, 0, bufA, tid, scol0);
    __syncthreads();                                  // wave-local drain

    for (int c = 0; c < NCHK; ++c) {
        float* cur = (c & 1) ? bufB : bufA;
        float* nxt = (c & 1) ? bufA : bufB;
        if (c < NCHK - 1) stage_chunk(sigb, c + 1, nxt, tid, scol0);
        chunkfma(cur, c, tid, y, wT);
        __syncthreads();                              // reads done + prefetch drained
    }

    // conv2 (1x1) + relu -> LDS (zero outside [0,N1) for convT zero-padding)
#pragma unroll
    for (int o = 0; o < CH; ++o) y[o] = fmaxf(y[o], 0.f);
#pragma unroll
    for (int o = 0; o < CH; ++o) {
        float a = b2[o];
#pragma unroll
        for (int i = 0; i < CH; ++i) a = fmaf(w2[o * CH + i], y[i], a);
        h2s[o * TPB + tid] = gvalid ? fmaxf(a, 0.f) : 0.f;
    }
    __syncthreads();

    // convT + relu + 1x1 + sigmoid -> lr at s = t0 + tid (tid < 62)
    const int s = t0 + tid;
    if (tid < TOUT + 2 && s < NN) {
        float acc[CH];
#pragma unroll
        for (int o = 0; o < CH; ++o) acc[o] = bt[o];
#pragma unroll
        for (int i = 0; i < CH; ++i) {
            const float a0 = h2s[i * TPB + tid];      // h2[s-2]
            const float a1 = h2s[i * TPB + tid + 1];  // h2[s-1]
            const float a2 = h2s[i * TPB + tid + 2];  // h2[s]
            const float* wp = wt + i * CH * 3;        // contiguous uniform
#pragma unroll
            for (int o = 0; o < CH; ++o) {
                acc[o] = fmaf(wp[o * 3 + 0], a2, acc[o]);
                acc[o] = fmaf(wp[o * 3 + 1], a1, acc[o]);
                acc[o] = fmaf(wp[o * 3 + 2], a0, acc[o]);
            }
        }
        float l = b3[0], r = b3[1];
#pragma unroll
        for (int o = 0; o < CH; ++o) {
            const float h3 = fmaxf(acc[o], 0.f);
            l = fmaf(w3[o],      h3, l);
            r = fmaf(w3[CH + o], h3, r);
        }
        lsh[tid] = 1.f / (1.f + __expf(-l));
        rsh[tid] = 1.f / (1.f + __expf(-r));
    }
    __syncthreads();

    // tridiagonal update + log for t = t0 + tid (tid < TOUT)
    float vlog = 0.f;
    const int t = t0 + tid;
    if (tid < TOUT && t < N1) {
        const float c0 = cd[(size_t)b * (NN - 1) + t];
        const float c1 = cd[(size_t)b * (NN - 1) + t + 1];
        const float mi = c1 * rsh[tid + 1] + c0 * lsh[tid + 1];
        const float mo = rsh[tid] + lsh[tid + 2];
        vlog = __logf(cstp[0] * mi / mo);
        outv[(size_t)b * N1 + t] = vlog;
    }

    // block sum: single-wave shuffle reduce
    float vs = vlog;
#pragma unroll
    for (int off = 32; off > 0; off >>= 1) vs += __shfl_down(vs, off);
    if (tid == 0)
        bsums[blockIdx.y * NTILE + blockIdx.x] = vs;
}

// K3: every block redundantly reduces the 4384 bsums (L2-hot), subtracts mean.
__global__ __launch_bounds__(256) void k3_meansub(
    const float* __restrict__ bsums, float* __restrict__ outv, int n)
{
    __shared__ float red[256];
    const int tid = threadIdx.x;
    float s = 0.f;
    for (int i = tid; i < NTILE * B; i += 256) s += bsums[i];
    red[tid] = s;
    __syncthreads();
#pragma unroll
    for (int st = 128; st > 0; st >>= 1) {
        if (tid < st) red[tid] += red[tid + st];
        __syncthreads();
    }
    const float mean = red[0] / (float)(B * N1);
    __syncthreads();
    const int i = blockIdx.x * 256 + tid;
    if (i < n) outv[i] -= mean;
}

extern "C" void kernel_launch(void* const* d_in, const int* in_sizes, int n_in,
                              void* d_out, int out_size, void* d_ws, size_t ws_size,
                              hipStream_t stream)
{
    const float* sig = (const float*)d_in[0];
    const float* cd  = (const float*)d_in[1];
    // d_in[2] = index_diag (1 for these shapes)
    const float* w1  = (const float*)d_in[3];
    const float* b1  = (const float*)d_in[4];
    const float* w2  = (const float*)d_in[5];
    const float* b2  = (const float*)d_in[6];
    const float* wt  = (const float*)d_in[7];
    const float* bt  = (const float*)d_in[8];
    const float* w3  = (const float*)d_in[9];
    const float* b3  = (const float*)d_in[10];
    const float* cst = (const float*)d_in[11];

    float* outv = (float*)d_out;

    // workspace layout (floats)
    float* ws   = (float*)d_ws;
    float* wT   = ws;                  // CIN*32 = 4096
    float* bsum = wT + CIN * 32;       // NTILE*B = 4384

    k0_prep   <<<dim3(16), dim3(256), 0, stream>>>(w1, wT);
    k_main    <<<dim3(NTILE, B), dim3(TPB), 0, stream>>>(sig, wT, b1, w2, b2,
                                                         wt, bt, w3, b3, cd, cst, outv, bsum);
    k3_meansub<<<dim3((out_size + 255) / 256), dim3(256), 0, stream>>>(bsum, outv, out_size);
}

// Round 10
// 271.357 us; speedup vs baseline: 1.1381x; 1.0074x over previous
//
#include <hip/hip_runtime.h>
#include <math.h>

#define B     32
#define CIN   128
#define NN    8192
#define N1    8190     // output length after k=3 valid conv
#define CH    10
#define TPB   64       // ONE wave per block (R7 structure, best-known 77.9us)
#define TOUT  60       // diag outputs per block
#define NTILE 137      // ceil(8190/60)
#define COLS  68       // staged cols per channel: [t0-4, t0+63], 17 float4
#define F4PC  17       // float4 per channel row
#define CPC   8        // channels per chunk
#define NCHK  16       // chunks

// K0: transpose w1[o][ci][k] -> wT[ci][o*3+k] (rows padded to 32 floats)
// so k_main's per-channel 30 weights are contiguous wave-uniform s_loads.
__global__ void k0_prep(const float* __restrict__ w1, float* __restrict__ wT)
{
    const int i = blockIdx.x * 256 + threadIdx.x;     // 0..4095
    if (i < CIN * 32) {
        const int ci = i >> 5, r = i & 31;
        float v = 0.f;
        if (r < 30) {
            const int o = r / 3, k = r - o * 3;
            v = w1[(o * CIN + ci) * 3 + k];
        }
        wT[i] = v;
    }
}

// Load one f4 of a chunk (f4 index i) from global. col is 16B-aligned
// (scol0 = t0-4 with t0 = 60*bx -> multiple of 4; clamps 0 and NN-4 too).
__device__ __forceinline__ float4 ldrow(const float* __restrict__ rowbase,
                                        int i, int scol0)
{
    const int row = (int)((unsigned)i / (unsigned)F4PC);
    int col = scol0 + (i - row * F4PC) * 4;
    col = col < 0 ? 0 : (col > NN - 4 ? NN - 4 : col); // clamped slots are
    return *(const float4*)(rowbase + (size_t)row * NN + col); // gvalid-masked
}

// FMA over one staged chunk. LDS float idx tid+2 <=> col g = t0-2+tid.
__device__ __forceinline__ void chunkfma(const float* __restrict__ cur, int c,
                                         int tid, float (&y)[CH],
                                         const float* __restrict__ wT)
{
    const float* bl = cur + tid + 2;
#pragma unroll
    for (int j = 0; j < CPC; ++j) {
        const float s0 = bl[j * COLS + 0];
        const float s1 = bl[j * COLS + 1];
        const float s2 = bl[j * COLS + 2];
        const float* wrow = wT + (c * CPC + j) * 32;  // uniform -> s_loads
#pragma unroll
        for (int o = 0; o < CH; ++o) {
            y[o] = fmaf(wrow[o * 3 + 0], s0, y[o]);
            y[o] = fmaf(wrow[o * 3 + 1], s1, y[o]);
            y[o] = fmaf(wrow[o * 3 + 2], s2, y[o]);
        }
    }
}

// K_MAIN: whole pipeline per 60-output tile, ONE WAVE per block.
// Diagnosis after R3-R9: every config staged via global_load_lds and every
// config pinned at ~1.0-1.4 TB/s effective read BW with ~3.3us/chunk waits
// (R6's L3-hot dispatch = same speed -> cap is between L2 and CU, i.e. the
// staging path itself, not HBM). This round swaps the LDS-DMA for
// REG-STAGING with the T14 issue-early/write-late split (HK's pattern,
// guide G15): loads for chunk c+1 are plain compiler-visible
// global_load_dwordx4 issued BEFORE chunkfma(c) (600cy hides latency);
// ds_write after the FMAs; then one __syncthreads. No asm, no fences.
__global__ __launch_bounds__(TPB) void k_main(
    const float* __restrict__ sig, const float* __restrict__ wT,
    const float* __restrict__ b1, const float* __restrict__ w2, const float* __restrict__ b2,
    const float* __restrict__ wt, const float* __restrict__ bt,
    const float* __restrict__ w3, const float* __restrict__ b3,
    const float* __restrict__ cd, const float* __restrict__ cstp,
    float* __restrict__ outv, float* __restrict__ bsums)
{
    __shared__ float bufA[CPC * COLS];   // 2176 B
    __shared__ float bufB[CPC * COLS];   // 2176 B
    __shared__ float h2s[CH * TPB];      // 2560 B  [o][col]
    __shared__ float lsh[TPB], rsh[TPB];

    const int tid = threadIdx.x;
    const int b   = blockIdx.y;
    const int t0  = blockIdx.x * TOUT;
    const int scol0 = t0 - 4;                         // 16B-aligned
    const int g   = t0 - 2 + tid;                     // h2 column of this thread
    const bool gvalid = (g >= 0) && (g < N1);
    const float* __restrict__ sigb = sig + (size_t)b * CIN * NN;

    float y[CH];
#pragma unroll
    for (int o = 0; o < CH; ++o) y[o] = b1[o];

    // ---- Phase 1: 16 chunks x 8 channels, reg-staged + T14 split ----
    {   // prologue: stage chunk 0 into bufA
        const float* rb = sigb;
        float4 v0 = ldrow(rb, tid, scol0);
        float4 v1 = ldrow(rb, 64 + tid, scol0);
        float4 v2 = {0,0,0,0};
        if (tid < 8) v2 = ldrow(rb, 128 + tid, scol0);
        *(float4*)(bufA + (size_t)tid * 4) = v0;
        *(float4*)(bufA + (size_t)(64 + tid) * 4) = v1;
        if (tid < 8) *(float4*)(bufA + (size_t)(128 + tid) * 4) = v2;
    }
    __syncthreads();

    for (int c = 0; c < NCHK; ++c) {
        float* cur = (c & 1) ? bufB : bufA;
        float* nxt = (c & 1) ? bufA : bufB;

        float4 v0, v1, v2;
        if (c < NCHK - 1) {                           // ISSUE EARLY (T14)
            const float* rb = sigb + (size_t)((c + 1) * CPC) * NN;
            v0 = ldrow(rb, tid, scol0);
            v1 = ldrow(rb, 64 + tid, scol0);
            if (tid < 8) v2 = ldrow(rb, 128 + tid, scol0);
        }

        chunkfma(cur, c, tid, y, wT);                 // latency hides here

        if (c < NCHK - 1) {                           // WRITE LATE (T14)
            *(float4*)(nxt + (size_t)tid * 4) = v0;
            *(float4*)(nxt + (size_t)(64 + tid) * 4) = v1;
            if (tid < 8) *(float4*)(nxt + (size_t)(128 + tid) * 4) = v2;
        }
        __syncthreads();                              // writes visible next iter
    }

    // conv2 (1x1) + relu -> LDS (zero outside [0,N1) for convT zero-padding)
#pragma unroll
    for (int o = 0; o < CH; ++o) y[o] = fmaxf(y[o], 0.f);
#pragma unroll
    for (int o = 0; o < CH; ++o) {
        float a = b2[o];
#pragma unroll
        for (int i = 0; i < CH; ++i) a = fmaf(w2[o * CH + i], y[i], a);
        h2s[o * TPB + tid] = gvalid ? fmaxf(a, 0.f) : 0.f;
    }
    __syncthreads();

    // convT + relu + 1x1 + sigmoid -> lr at s = t0 + tid (tid < 62)
    const int s = t0 + tid;
    if (tid < TOUT + 2 && s < NN) {
        float acc[CH];
#pragma unroll
        for (int o = 0; o < CH; ++o) acc[o] = bt[o];
#pragma unroll
        for (int i = 0; i < CH; ++i) {
            const float a0 = h2s[i * TPB + tid];      // h2[s-2]
            const float a1 = h2s[i * TPB + tid + 1];  // h2[s-1]
            const float a2 = h2s[i * TPB + tid + 2];  // h2[s]
            const float* wp = wt + i * CH * 3;        // contiguous uniform
#pragma unroll
            for (int o = 0; o < CH; ++o) {
                acc[o] = fmaf(wp[o * 3 + 0], a2, acc[o]);
                acc[o] = fmaf(wp[o * 3 + 1], a1, acc[o]);
                acc[o] = fmaf(wp[o * 3 + 2], a0, acc[o]);
            }
        }
        float l = b3[0], r = b3[1];
#pragma unroll
        for (int o = 0; o < CH; ++o) {
            const float h3 = fmaxf(acc[o], 0.f);
            l = fmaf(w3[o],      h3, l);
            r = fmaf(w3[CH + o], h3, r);
        }
        lsh[tid] = 1.f / (1.f + __expf(-l));
        rsh[tid] = 1.f / (1.f + __expf(-r));
    }
    __syncthreads();

    // tridiagonal update + log for t = t0 + tid (tid < TOUT)
    float vlog = 0.f;
    const int t = t0 + tid;
    if (tid < TOUT && t < N1) {
        const float c0 = cd[(size_t)b * (NN - 1) + t];
        const float c1 = cd[(size_t)b * (NN - 1) + t + 1];
        const float mi = c1 * rsh[tid + 1] + c0 * lsh[tid + 1];
        const float mo = rsh[tid] + lsh[tid + 2];
        vlog = __logf(cstp[0] * mi / mo);
        outv[(size_t)b * N1 + t] = vlog;
    }

    // block sum: single-wave shuffle reduce
    float vs = vlog;
#pragma unroll
    for (int off = 32; off > 0; off >>= 1) vs += __shfl_down(vs, off);
    if (tid == 0)
        bsums[blockIdx.y * NTILE + blockIdx.x] = vs;
}

// K3: every block redundantly reduces the 4384 bsums (L2-hot), subtracts mean.
__global__ __launch_bounds__(256) void k3_meansub(
    const float* __restrict__ bsums, float* __restrict__ outv, int n)
{
    __shared__ float red[256];
    const int tid = threadIdx.x;
    float s = 0.f;
    for (int i = tid; i < NTILE * B; i += 256) s += bsums[i];
    red[tid] = s;
    __syncthreads();
#pragma unroll
    for (int st = 128; st > 0; st >>= 1) {
        if (tid < st) red[tid] += red[tid + st];
        __syncthreads();
    }
    const float mean = red[0] / (float)(B * N1);
    __syncthreads();
    const int i = blockIdx.x * 256 + tid;
    if (i < n) outv[i] -= mean;
}

extern "C" void kernel_launch(void* const* d_in, const int* in_sizes, int n_in,
                              void* d_out, int out_size, void* d_ws, size_t ws_size,
                              hipStream_t stream)
{
    const float* sig = (const float*)d_in[0];
    const float* cd  = (const float*)d_in[1];
    // d_in[2] = index_diag (1 for these shapes)
    const float* w1  = (const float*)d_in[3];
    const float* b1  = (const float*)d_in[4];
    const float* w2  = (const float*)d_in[5];
    const float* b2  = (const float*)d_in[6];
    const float* wt  = (const float*)d_in[7];
    const float* bt  = (const float*)d_in[8];
    const float* w3  = (const float*)d_in[9];
    const float* b3  = (const float*)d_in[10];
    const float* cst = (const float*)d_in[11];

    float* outv = (float*)d_out;

    // workspace layout (floats)
    float* ws   = (float*)d_ws;
    float* wT   = ws;                  // CIN*32 = 4096
    float* bsum = wT + CIN * 32;       // NTILE*B = 4384

    k0_prep   <<<dim3(16), dim3(256), 0, stream>>>(w1, wT);
    k_main    <<<dim3(NTILE, B), dim3(TPB), 0, stream>>>(sig, wT, b1, w2, b2,
                                                         wt, bt, w3, b3, cd, cst, outv, bsum);
    k3_meansub<<<dim3((out_size + 255) / 256), dim3(256), 0, stream>>>(bsum, outv, out_size);
}